// Round 1
// baseline (355.951 us; speedup 1.0000x reference)
//
#include <hip/hip_runtime.h>
#include <hip/hip_bf16.h>
#include <math.h>

#define DEP   96
#define HEADS 96
#define BSZ   16
#define DIM   512
#define REL   128
#define RELP  129   // REL + nil

// ---------------------------------------------------------------------------
// Kernel A: projections (GEMM-NT), both halves of Wt in one launch (blockIdx.z)
//   z=0: P1[m][n] = sum_k outs[m][k]  * Wt[n*1024 + k]       + bt[n]
//   z=1: P2[m][n] = sum_k graph[m][k] * Wt[n*1024 + 512 + k]
// M=1536, N=512, K=512. 64x64 tile, BK=16, 256 threads, 4x4 per thread.
// ---------------------------------------------------------------------------
__global__ __launch_bounds__(256) void proj_kernel(
    const float* __restrict__ outs, const float* __restrict__ graph,
    const float* __restrict__ Wt,   const float* __restrict__ bt,
    float* __restrict__ P1, float* __restrict__ P2)
{
    const int z = blockIdx.z;
    const float* A = z ? graph : outs;
    float* C = z ? P2 : P1;
    const int off  = z ? DIM : 0;
    const int row0 = blockIdx.y * 64;
    const int col0 = blockIdx.x * 64;

    __shared__ float As[16][68];   // [k][m], padded (68%4==0 keeps f4 alignment)
    __shared__ float Bs[16][68];   // [k][n]

    const int tid = threadIdx.x;
    const int tx = tid & 15, ty = tid >> 4;
    const int lm = tid >> 2;          // 0..63
    const int lk = (tid & 3) * 4;     // 0,4,8,12

    float acc[4][4] = {};

    for (int kt = 0; kt < DIM; kt += 16) {
        float4 av = *(const float4*)(A  + (size_t)(row0 + lm) * DIM       + kt + lk);
        float4 bv = *(const float4*)(Wt + (size_t)(col0 + lm) * (2*DIM) + off + kt + lk);
        As[lk+0][lm] = av.x; As[lk+1][lm] = av.y; As[lk+2][lm] = av.z; As[lk+3][lm] = av.w;
        Bs[lk+0][lm] = bv.x; Bs[lk+1][lm] = bv.y; Bs[lk+2][lm] = bv.z; Bs[lk+3][lm] = bv.w;
        __syncthreads();
        #pragma unroll
        for (int k = 0; k < 16; ++k) {
            float4 a = *(const float4*)&As[k][ty*4];
            float4 b = *(const float4*)&Bs[k][tx*4];
            float aa[4] = {a.x,a.y,a.z,a.w};
            float bb[4] = {b.x,b.y,b.z,b.w};
            #pragma unroll
            for (int i = 0; i < 4; ++i)
                #pragma unroll
                for (int j = 0; j < 4; ++j) acc[i][j] += aa[i]*bb[j];
        }
        __syncthreads();
    }

    #pragma unroll
    for (int i = 0; i < 4; ++i) {
        const int m = row0 + ty*4 + i;
        #pragma unroll
        for (int j = 0; j < 4; ++j) {
            const int n = col0 + tx*4 + j;
            float v = acc[i][j];
            if (!z) v += bt[n];          // fold bt into dep projection once
            C[(size_t)m * DIM + n] = v;
        }
    }
}

// ---------------------------------------------------------------------------
// Kernel B: fused pairwise relu-GEMM + bias + log_softmax(129) + store.
// One block per (d,b). C[96 h][128 r] = relu(P1row + P2[h,b,:]) @ Wp^T + bp.
// 256 threads as 16x16; each thread owns a 6(h) x 8(r) micro-tile.
// ---------------------------------------------------------------------------
__global__ __launch_bounds__(256) void fused_kernel(
    const float* __restrict__ P1, const float* __restrict__ P2,
    const float* __restrict__ Wp, const float* __restrict__ bp,
    float* __restrict__ out)
{
    const int db = blockIdx.x;       // d*16 + b
    const int b  = db & 15;

    __shared__ float drow[DIM];        // dep row, bt folded
    __shared__ float hvt[16][100];     // [e][h]  relu(dep+head), padded
    __shared__ float wpt[16][132];     // [e][r]  Wp^T chunk, padded

    const int tid = threadIdx.x;
    const int tx = tid & 15, ty = tid >> 4;

    drow[tid]       = P1[(size_t)db * DIM + tid];
    drow[tid + 256] = P1[(size_t)db * DIM + tid + 256];
    __syncthreads();

    float acc[6][8] = {};

    const int se  = tid & 15;            // staging e (hvt)
    const int shb = (tid >> 4) * 6;      // staging h base (hvt)
    const int sr  = tid >> 1;            // staging r (wpt)
    const int se0 = (tid & 1) * 8;       // staging e base (wpt)

    for (int kt = 0; kt < DIM; kt += 16) {
        // stage hvt[e][h] = relu(drow[e] + P2[h,b,e])
        #pragma unroll
        for (int q = 0; q < 6; ++q) {
            const int h = shb + q;
            float v = drow[kt + se] + P2[((size_t)h * BSZ + b) * DIM + kt + se];
            hvt[se][h] = v > 0.f ? v : 0.f;
        }
        // stage wpt[e][r] (transpose of Wp[r][e])
        {
            float4 v0 = *(const float4*)(Wp + (size_t)sr * DIM + kt + se0);
            float4 v1 = *(const float4*)(Wp + (size_t)sr * DIM + kt + se0 + 4);
            wpt[se0+0][sr] = v0.x; wpt[se0+1][sr] = v0.y;
            wpt[se0+2][sr] = v0.z; wpt[se0+3][sr] = v0.w;
            wpt[se0+4][sr] = v1.x; wpt[se0+5][sr] = v1.y;
            wpt[se0+6][sr] = v1.z; wpt[se0+7][sr] = v1.w;
        }
        __syncthreads();
        #pragma unroll
        for (int e = 0; e < 16; ++e) {
            float a[6];
            #pragma unroll
            for (int i = 0; i < 6; ++i) a[i] = hvt[e][ty*6 + i];
            float4 b0 = *(const float4*)&wpt[e][tx*8];
            float4 b1 = *(const float4*)&wpt[e][tx*8 + 4];
            float bb[8] = {b0.x,b0.y,b0.z,b0.w,b1.x,b1.y,b1.z,b1.w};
            #pragma unroll
            for (int i = 0; i < 6; ++i)
                #pragma unroll
                for (int j = 0; j < 8; ++j) acc[i][j] += a[i]*bb[j];
        }
        __syncthreads();
    }

    // bias + log_softmax over {nil=0} ∪ scores, then store.
    // Row h is owned by the 16 lanes sharing ty (contiguous lanes in a wave).
    #pragma unroll
    for (int i = 0; i < 6; ++i) {
        const int h = ty*6 + i;
        float s[8];
        float m = 0.f;                    // nil element participates in max
        #pragma unroll
        for (int j = 0; j < 8; ++j) {
            s[j] = acc[i][j] + bp[tx*8 + j];
            m = fmaxf(m, s[j]);
        }
        #pragma unroll
        for (int mask = 1; mask < 16; mask <<= 1) m = fmaxf(m, __shfl_xor(m, mask));
        float l = 0.f;
        #pragma unroll
        for (int j = 0; j < 8; ++j) l += __expf(s[j] - m);
        #pragma unroll
        for (int mask = 1; mask < 16; mask <<= 1) l += __shfl_xor(l, mask);
        l += __expf(-m);                  // nil term
        const float lse = m + __logf(l);

        const size_t base = ((size_t)db * HEADS + h) * RELP;
        #pragma unroll
        for (int j = 0; j < 8; ++j) out[base + 1 + tx*8 + j] = s[j] - lse;
        if (tx == 0) out[base] = -lse;
    }
}

extern "C" void kernel_launch(void* const* d_in, const int* in_sizes, int n_in,
                              void* d_out, int out_size, void* d_ws, size_t ws_size,
                              hipStream_t stream) {
    const float* outs  = (const float*)d_in[0];
    const float* graph = (const float*)d_in[1];
    const float* Wt    = (const float*)d_in[2];
    const float* bt    = (const float*)d_in[3];
    const float* Wp    = (const float*)d_in[4];
    const float* bp    = (const float*)d_in[5];
    float* out = (float*)d_out;

    float* P1 = (float*)d_ws;                          // [1536][512]
    float* P2 = P1 + (size_t)DEP * BSZ * DIM;          // [1536][512]

    proj_kernel<<<dim3(DIM/64, (DEP*BSZ)/64, 2), 256, 0, stream>>>(
        outs, graph, Wt, bt, P1, P2);
    fused_kernel<<<DEP*BSZ, 256, 0, stream>>>(P1, P2, Wp, bp, out);
}

// Round 2
// 173.680 us; speedup vs baseline: 2.0495x; 2.0495x over previous
//
#include <hip/hip_runtime.h>
#include <hip/hip_bf16.h>
#include <math.h>

#define DEP   96
#define HEADS 96
#define BSZ   16
#define DIM   512
#define REL   128
#define RELP  129   // REL + nil

typedef __attribute__((ext_vector_type(8))) short short8;
typedef __attribute__((ext_vector_type(4))) float floatx4;

__device__ __forceinline__ unsigned short f2bf(float x) {
    union { float f; unsigned int u; } c; c.f = x;
    unsigned int r = c.u + 0x7fffu + ((c.u >> 16) & 1u);   // RNE
    return (unsigned short)(r >> 16);
}

// ---------------------------------------------------------------------------
// Kernel A: projections (GEMM-NT, fp32), both halves of Wt via blockIdx.z
// ---------------------------------------------------------------------------
__global__ __launch_bounds__(256) void proj_kernel(
    const float* __restrict__ outs, const float* __restrict__ graph,
    const float* __restrict__ Wt,   const float* __restrict__ bt,
    float* __restrict__ P1, float* __restrict__ P2)
{
    const int z = blockIdx.z;
    const float* A = z ? graph : outs;
    float* C = z ? P2 : P1;
    const int off  = z ? DIM : 0;
    const int row0 = blockIdx.y * 64;
    const int col0 = blockIdx.x * 64;

    __shared__ float As[16][68];
    __shared__ float Bs[16][68];

    const int tid = threadIdx.x;
    const int tx = tid & 15, ty = tid >> 4;
    const int lm = tid >> 2;
    const int lk = (tid & 3) * 4;

    float acc[4][4] = {};

    for (int kt = 0; kt < DIM; kt += 16) {
        float4 av = *(const float4*)(A  + (size_t)(row0 + lm) * DIM       + kt + lk);
        float4 bv = *(const float4*)(Wt + (size_t)(col0 + lm) * (2*DIM) + off + kt + lk);
        As[lk+0][lm] = av.x; As[lk+1][lm] = av.y; As[lk+2][lm] = av.z; As[lk+3][lm] = av.w;
        Bs[lk+0][lm] = bv.x; Bs[lk+1][lm] = bv.y; Bs[lk+2][lm] = bv.z; Bs[lk+3][lm] = bv.w;
        __syncthreads();
        #pragma unroll
        for (int k = 0; k < 16; ++k) {
            float4 a = *(const float4*)&As[k][ty*4];
            float4 b = *(const float4*)&Bs[k][tx*4];
            float aa[4] = {a.x,a.y,a.z,a.w};
            float bb[4] = {b.x,b.y,b.z,b.w};
            #pragma unroll
            for (int i = 0; i < 4; ++i)
                #pragma unroll
                for (int j = 0; j < 4; ++j) acc[i][j] += aa[i]*bb[j];
        }
        __syncthreads();
    }

    #pragma unroll
    for (int i = 0; i < 4; ++i) {
        const int m = row0 + ty*4 + i;
        #pragma unroll
        for (int j = 0; j < 4; ++j) {
            const int n = col0 + tx*4 + j;
            float v = acc[i][j];
            if (!z) v += bt[n];
            C[(size_t)m * DIM + n] = v;
        }
    }
}

// ---------------------------------------------------------------------------
// Kernel W: Wp fp32 -> bf16 (once; shared across all 1536 fused blocks)
// ---------------------------------------------------------------------------
__global__ __launch_bounds__(256) void wp_cvt_kernel(
    const float* __restrict__ Wp, unsigned short* __restrict__ WpB)
{
    const int i = blockIdx.x * 256 + threadIdx.x;     // 16384 threads, 4 elems each
    float4 v = *(const float4*)(Wp + (size_t)i * 4);
    ushort4 o;
    o.x = f2bf(v.x); o.y = f2bf(v.y); o.z = f2bf(v.z); o.w = f2bf(v.w);
    *(ushort4*)(WpB + (size_t)i * 4) = o;
}

// ---------------------------------------------------------------------------
// Kernel B: fused pairwise relu + bf16-MFMA GEMM + log_softmax(129).
// One block per (d,b): C[96 m][128 n] = relu(drow + P2[h,b,:]) @ Wp^T.
// 128 threads = 2 waves; wave w owns rows [48w,48w+48) x all 128 cols.
// mfma_f32_16x16x32_bf16: A[m=lane&15][k=quad*8+j], B[k=quad*8+j][n=lane&15],
// D row=quad*4+reg, col=lane&15 (m89/m120-verified layouts).
// ---------------------------------------------------------------------------
#define HSS 72   // hs row stride (bf16 elems): 144 B, 16B-aligned, 2-way banks (free)
#define WSS 72

__global__ __launch_bounds__(128, 2) void fused_kernel(
    const float* __restrict__ P1, const float* __restrict__ P2,
    const unsigned short* __restrict__ WpB, const float* __restrict__ bp,
    float* __restrict__ out)
{
    const int db = blockIdx.x;      // d*16 + b
    const int b  = db & 15;

    __shared__ float          drow[DIM];
    __shared__ unsigned short hs[96 * HSS];    // h tile  [m][k] bf16
    __shared__ unsigned short ws[128 * WSS];   // Wp tile [n][k] bf16

    const int tid  = threadIdx.x;       // 0..127
    const int lane = tid & 63;
    const int wv   = tid >> 6;          // 0..1
    const int ln15 = lane & 15;
    const int quad = lane >> 4;

    // stage dep row (bt already folded by proj)
    #pragma unroll
    for (int q = 0; q < 4; ++q) drow[q*128 + tid] = P1[(size_t)db * DIM + q*128 + tid];
    __syncthreads();

    floatx4 acc[3][8];
    #pragma unroll
    for (int i = 0; i < 3; ++i)
        #pragma unroll
        for (int j = 0; j < 8; ++j) acc[i][j] = (floatx4){0.f,0.f,0.f,0.f};

    for (int kt = 0; kt < DIM; kt += 64) {
        // ---- stage hs[h][e] = bf16(relu(drow[e] + P2[h,b,e])), 96x64 ----
        #pragma unroll
        for (int q = 0; q < 12; ++q) {
            const int slot = q*128 + tid;        // 0..1535
            const int h  = slot >> 4;
            const int e4 = (slot & 15) * 4;
            float4 p = *(const float4*)(P2 + ((size_t)h * BSZ + b) * DIM + kt + e4);
            float4 d = *(const float4*)&drow[kt + e4];
            ushort4 o;
            o.x = f2bf(fmaxf(p.x + d.x, 0.f));
            o.y = f2bf(fmaxf(p.y + d.y, 0.f));
            o.z = f2bf(fmaxf(p.z + d.z, 0.f));
            o.w = f2bf(fmaxf(p.w + d.w, 0.f));
            *(ushort4*)&hs[h * HSS + e4] = o;
        }
        // ---- stage ws[r][e] = WpB[r][kt+e], 128x64 (B-operand layout) ----
        #pragma unroll
        for (int q = 0; q < 8; ++q) {
            const int slot = q*128 + tid;        // 0..1023
            const int r = slot >> 3;
            const int g = (slot & 7) * 8;
            uint4 v = *(const uint4*)(WpB + (size_t)r * DIM + kt + g);
            *(uint4*)&ws[r * WSS + g] = v;
        }
        __syncthreads();

        #pragma unroll
        for (int ks = 0; ks < 64; ks += 32) {
            short8 af[3], bf8[8];
            #pragma unroll
            for (int mt = 0; mt < 3; ++mt)
                af[mt] = *(const short8*)&hs[(wv*48 + mt*16 + ln15) * HSS + ks + quad*8];
            #pragma unroll
            for (int nt = 0; nt < 8; ++nt)
                bf8[nt] = *(const short8*)&ws[(nt*16 + ln15) * WSS + ks + quad*8];
            #pragma unroll
            for (int nt = 0; nt < 8; ++nt)
                #pragma unroll
                for (int mt = 0; mt < 3; ++mt)
                    acc[mt][nt] = __builtin_amdgcn_mfma_f32_16x16x32_bf16(
                        af[mt], bf8[nt], acc[mt][nt], 0, 0, 0);
        }
        __syncthreads();
    }

    // ---- epilogue: bias + log_softmax over {nil=0} U 128 scores ----
    float bpv[8];
    #pragma unroll
    for (int nt = 0; nt < 8; ++nt) bpv[nt] = bp[nt*16 + ln15];

    #pragma unroll
    for (int mt = 0; mt < 3; ++mt) {
        #pragma unroll
        for (int reg = 0; reg < 4; ++reg) {
            const int m = wv*48 + mt*16 + quad*4 + reg;
            float s[8];
            float mx = 0.f;                          // nil participates in max
            #pragma unroll
            for (int nt = 0; nt < 8; ++nt) {
                s[nt] = acc[mt][nt][reg] + bpv[nt];
                mx = fmaxf(mx, s[nt]);
            }
            #pragma unroll
            for (int msk = 1; msk < 16; msk <<= 1) mx = fmaxf(mx, __shfl_xor(mx, msk));
            float l = 0.f;
            #pragma unroll
            for (int nt = 0; nt < 8; ++nt) l += __expf(s[nt] - mx);
            #pragma unroll
            for (int msk = 1; msk < 16; msk <<= 1) l += __shfl_xor(l, msk);
            l += __expf(-mx);                        // nil term
            const float lse = mx + __logf(l);

            const size_t base = ((size_t)db * HEADS + m) * RELP;
            #pragma unroll
            for (int nt = 0; nt < 8; ++nt) out[base + 1 + nt*16 + ln15] = s[nt] - lse;
            if (ln15 == 0) out[base] = -lse;
        }
    }
}

extern "C" void kernel_launch(void* const* d_in, const int* in_sizes, int n_in,
                              void* d_out, int out_size, void* d_ws, size_t ws_size,
                              hipStream_t stream) {
    const float* outs  = (const float*)d_in[0];
    const float* graph = (const float*)d_in[1];
    const float* Wt    = (const float*)d_in[2];
    const float* bt    = (const float*)d_in[3];
    const float* Wp    = (const float*)d_in[4];
    const float* bp    = (const float*)d_in[5];
    float* out = (float*)d_out;

    float* P1 = (float*)d_ws;                              // [1536][512] f32
    float* P2 = P1 + (size_t)DEP * BSZ * DIM;              // [1536][512] f32
    unsigned short* WpB = (unsigned short*)(P2 + (size_t)DEP * BSZ * DIM);  // [128][512] bf16

    wp_cvt_kernel<<<REL * DIM / (256 * 4), 256, 0, stream>>>(Wp, WpB);
    proj_kernel<<<dim3(DIM/64, (DEP*BSZ)/64, 2), 256, 0, stream>>>(
        outs, graph, Wt, bt, P1, P2);
    fused_kernel<<<DEP*BSZ, 128, 0, stream>>>(P1, P2, WpB, bp, out);
}

// Round 3
// 163.949 us; speedup vs baseline: 2.1711x; 1.0594x over previous
//
#include <hip/hip_runtime.h>
#include <hip/hip_bf16.h>
#include <math.h>

#define DEP   96
#define HEADS 96
#define BSZ   16
#define DIM   512
#define REL   128
#define RELP  129   // REL + nil

typedef __attribute__((ext_vector_type(8))) short short8;
typedef __attribute__((ext_vector_type(4))) float floatx4;

__device__ __forceinline__ unsigned short f2bf(float x) {
    union { float f; unsigned int u; } c; c.f = x;
    unsigned int r = c.u + 0x7fffu + ((c.u >> 16) & 1u);   // RNE
    return (unsigned short)(r >> 16);
}
__device__ __forceinline__ float bflo2f(unsigned int u) {
    union { unsigned int u; float f; } c; c.u = u << 16; return c.f;
}
__device__ __forceinline__ float bfhi2f(unsigned int u) {
    union { unsigned int u; float f; } c; c.u = u & 0xffff0000u; return c.f;
}

#define PSS 72   // LDS row stride (bf16 elems): 144 B = 16B-aligned, 2-way banks (free)

// ---------------------------------------------------------------------------
// Kernel A: projections via bf16 MFMA (cast-on-stage). blockIdx.z selects half.
//   z=0: P1[m][n] = sum_k outs[m][k]*Wt[n*1024+k]     + bt[n]   (f32 out)
//   z=1: P2B[m][n]= sum_k graph[m][k]*Wt[n*1024+512+k]          (bf16 out)
// 64x64 tile, BK=64, 256 threads = 4 waves; wave w owns m-rows [16w,16w+16).
// mfma_f32_16x16x32_bf16 layouts (m89/m120-verified, same as fused_kernel).
// ---------------------------------------------------------------------------
__global__ __launch_bounds__(256) void proj_kernel(
    const float* __restrict__ outs, const float* __restrict__ graph,
    const float* __restrict__ Wt,   const float* __restrict__ bt,
    float* __restrict__ P1, unsigned short* __restrict__ P2B)
{
    const int z = blockIdx.z;
    const float* A = z ? graph : outs;
    const int off  = z ? DIM : 0;
    const int row0 = blockIdx.y * 64;
    const int col0 = blockIdx.x * 64;

    __shared__ unsigned short As[64 * PSS];   // [m][k] bf16
    __shared__ unsigned short Ws[64 * PSS];   // [n][k] bf16

    const int tid  = threadIdx.x;
    const int lane = tid & 63;
    const int wv   = tid >> 6;          // 0..3
    const int ln15 = lane & 15;
    const int quad = lane >> 4;

    floatx4 acc[4];
    #pragma unroll
    for (int nt = 0; nt < 4; ++nt) acc[nt] = (floatx4){0.f,0.f,0.f,0.f};

    for (int kt = 0; kt < DIM; kt += 64) {
        #pragma unroll
        for (int q = 0; q < 4; ++q) {
            const int slot = q*256 + tid;       // 0..1023
            const int r  = slot >> 4;           // 0..63
            const int e4 = (slot & 15) * 4;
            float4 v = *(const float4*)(A + (size_t)(row0 + r) * DIM + kt + e4);
            ushort4 o;
            o.x = f2bf(v.x); o.y = f2bf(v.y); o.z = f2bf(v.z); o.w = f2bf(v.w);
            *(ushort4*)&As[r * PSS + e4] = o;
        }
        #pragma unroll
        for (int q = 0; q < 4; ++q) {
            const int slot = q*256 + tid;
            const int r  = slot >> 4;
            const int e4 = (slot & 15) * 4;
            float4 v = *(const float4*)(Wt + (size_t)(col0 + r) * (2*DIM) + off + kt + e4);
            ushort4 o;
            o.x = f2bf(v.x); o.y = f2bf(v.y); o.z = f2bf(v.z); o.w = f2bf(v.w);
            *(ushort4*)&Ws[r * PSS + e4] = o;
        }
        __syncthreads();
        #pragma unroll
        for (int ks = 0; ks < 64; ks += 32) {
            short8 af = *(const short8*)&As[(wv*16 + ln15) * PSS + ks + quad*8];
            #pragma unroll
            for (int nt = 0; nt < 4; ++nt) {
                short8 bf8 = *(const short8*)&Ws[(nt*16 + ln15) * PSS + ks + quad*8];
                acc[nt] = __builtin_amdgcn_mfma_f32_16x16x32_bf16(af, bf8, acc[nt], 0, 0, 0);
            }
        }
        __syncthreads();
    }

    #pragma unroll
    for (int nt = 0; nt < 4; ++nt) {
        #pragma unroll
        for (int reg = 0; reg < 4; ++reg) {
            const int m = row0 + wv*16 + quad*4 + reg;
            const int n = col0 + nt*16 + ln15;
            float v = acc[nt][reg];
            if (!z) P1[(size_t)m * DIM + n] = v + bt[n];
            else    P2B[(size_t)m * DIM + n] = f2bf(v);
        }
    }
}

// ---------------------------------------------------------------------------
// Kernel W: Wp fp32 -> bf16 (once; shared across all 1536 fused blocks)
// ---------------------------------------------------------------------------
__global__ __launch_bounds__(256) void wp_cvt_kernel(
    const float* __restrict__ Wp, unsigned short* __restrict__ WpB)
{
    const int i = blockIdx.x * 256 + threadIdx.x;
    float4 v = *(const float4*)(Wp + (size_t)i * 4);
    ushort4 o;
    o.x = f2bf(v.x); o.y = f2bf(v.y); o.z = f2bf(v.z); o.w = f2bf(v.w);
    *(ushort4*)(WpB + (size_t)i * 4) = o;
}

// ---------------------------------------------------------------------------
// Kernel B: fused pairwise relu + bf16-MFMA GEMM + log_softmax(129).
// One block per (d,b): C[96 m][128 n] = relu(drow + P2[h,b,:]) @ Wp^T.
// 128 threads = 2 waves; wave w owns rows [48w,48w+48) x all 128 cols.
// ---------------------------------------------------------------------------
#define HSS 72
#define WSS 72

__global__ __launch_bounds__(128, 2) void fused_kernel(
    const float* __restrict__ P1, const unsigned short* __restrict__ P2B,
    const unsigned short* __restrict__ WpB, const float* __restrict__ bp,
    float* __restrict__ out)
{
    const int db = blockIdx.x;      // d*16 + b
    const int b  = db & 15;

    __shared__ float          drow[DIM];
    __shared__ unsigned short hs[96 * HSS];    // h tile  [m][k] bf16
    __shared__ unsigned short ws[128 * WSS];   // Wp tile [n][k] bf16

    const int tid  = threadIdx.x;       // 0..127
    const int lane = tid & 63;
    const int wv   = tid >> 6;          // 0..1
    const int ln15 = lane & 15;
    const int quad = lane >> 4;

    #pragma unroll
    for (int q = 0; q < 4; ++q) drow[q*128 + tid] = P1[(size_t)db * DIM + q*128 + tid];
    __syncthreads();

    floatx4 acc[3][8];
    #pragma unroll
    for (int i = 0; i < 3; ++i)
        #pragma unroll
        for (int j = 0; j < 8; ++j) acc[i][j] = (floatx4){0.f,0.f,0.f,0.f};

    for (int kt = 0; kt < DIM; kt += 64) {
        // ---- stage hs[h][e] = bf16(relu(drow[e] + P2B[h,b,e])), 96x64 ----
        #pragma unroll
        for (int q = 0; q < 6; ++q) {
            const int slot = q*128 + tid;        // 0..767
            const int h  = slot >> 3;            // 0..95
            const int e8 = (slot & 7) * 8;
            uint4 pv = *(const uint4*)(P2B + ((size_t)h * BSZ + b) * DIM + kt + e8);
            float4 d0 = *(const float4*)&drow[kt + e8];
            float4 d1 = *(const float4*)&drow[kt + e8 + 4];
            float s0 = fmaxf(bflo2f(pv.x) + d0.x, 0.f);
            float s1 = fmaxf(bfhi2f(pv.x) + d0.y, 0.f);
            float s2 = fmaxf(bflo2f(pv.y) + d0.z, 0.f);
            float s3 = fmaxf(bfhi2f(pv.y) + d0.w, 0.f);
            float s4 = fmaxf(bflo2f(pv.z) + d1.x, 0.f);
            float s5 = fmaxf(bfhi2f(pv.z) + d1.y, 0.f);
            float s6 = fmaxf(bflo2f(pv.w) + d1.z, 0.f);
            float s7 = fmaxf(bfhi2f(pv.w) + d1.w, 0.f);
            uint2 o0, o1;
            o0.x = (unsigned)f2bf(s0) | ((unsigned)f2bf(s1) << 16);
            o0.y = (unsigned)f2bf(s2) | ((unsigned)f2bf(s3) << 16);
            o1.x = (unsigned)f2bf(s4) | ((unsigned)f2bf(s5) << 16);
            o1.y = (unsigned)f2bf(s6) | ((unsigned)f2bf(s7) << 16);
            *(uint2*)&hs[h * HSS + e8]     = o0;
            *(uint2*)&hs[h * HSS + e8 + 4] = o1;
        }
        // ---- stage ws[r][e] = WpB[r][kt+e], 128x64 (B-operand layout) ----
        #pragma unroll
        for (int q = 0; q < 8; ++q) {
            const int slot = q*128 + tid;        // 0..1023
            const int r = slot >> 3;
            const int g = (slot & 7) * 8;
            uint4 v = *(const uint4*)(WpB + (size_t)r * DIM + kt + g);
            *(uint4*)&ws[r * WSS + g] = v;
        }
        __syncthreads();

        #pragma unroll
        for (int ks = 0; ks < 64; ks += 32) {
            short8 af[3], bf8[8];
            #pragma unroll
            for (int mt = 0; mt < 3; ++mt)
                af[mt] = *(const short8*)&hs[(wv*48 + mt*16 + ln15) * HSS + ks + quad*8];
            #pragma unroll
            for (int nt = 0; nt < 8; ++nt)
                bf8[nt] = *(const short8*)&ws[(nt*16 + ln15) * WSS + ks + quad*8];
            #pragma unroll
            for (int nt = 0; nt < 8; ++nt)
                #pragma unroll
                for (int mt = 0; mt < 3; ++mt)
                    acc[mt][nt] = __builtin_amdgcn_mfma_f32_16x16x32_bf16(
                        af[mt], bf8[nt], acc[mt][nt], 0, 0, 0);
        }
        __syncthreads();
    }

    // ---- epilogue: bias + log_softmax over {nil=0} U 128 scores ----
    float bpv[8];
    #pragma unroll
    for (int nt = 0; nt < 8; ++nt) bpv[nt] = bp[nt*16 + ln15];

    #pragma unroll
    for (int mt = 0; mt < 3; ++mt) {
        #pragma unroll
        for (int reg = 0; reg < 4; ++reg) {
            const int m = wv*48 + mt*16 + quad*4 + reg;
            float s[8];
            float mx = 0.f;                          // nil participates in max
            #pragma unroll
            for (int nt = 0; nt < 8; ++nt) {
                s[nt] = acc[mt][nt][reg] + bpv[nt];
                mx = fmaxf(mx, s[nt]);
            }
            #pragma unroll
            for (int msk = 1; msk < 16; msk <<= 1) mx = fmaxf(mx, __shfl_xor(mx, msk));
            float l = 0.f;
            #pragma unroll
            for (int nt = 0; nt < 8; ++nt) l += __expf(s[nt] - mx);
            #pragma unroll
            for (int msk = 1; msk < 16; msk <<= 1) l += __shfl_xor(l, msk);
            l += __expf(-mx);                        // nil term
            const float lse = mx + __logf(l);

            const size_t base = ((size_t)db * HEADS + m) * RELP;
            #pragma unroll
            for (int nt = 0; nt < 8; ++nt) out[base + 1 + nt*16 + ln15] = s[nt] - lse;
            if (ln15 == 0) out[base] = -lse;
        }
    }
}

extern "C" void kernel_launch(void* const* d_in, const int* in_sizes, int n_in,
                              void* d_out, int out_size, void* d_ws, size_t ws_size,
                              hipStream_t stream) {
    const float* outs  = (const float*)d_in[0];
    const float* graph = (const float*)d_in[1];
    const float* Wt    = (const float*)d_in[2];
    const float* bt    = (const float*)d_in[3];
    const float* Wp    = (const float*)d_in[4];
    const float* bp    = (const float*)d_in[5];
    float* out = (float*)d_out;

    float* P1 = (float*)d_ws;                                   // [1536][512] f32
    unsigned short* P2B = (unsigned short*)(P1 + (size_t)DEP * BSZ * DIM);   // [1536][512] bf16
    unsigned short* WpB = P2B + (size_t)DEP * BSZ * DIM;        // [128][512] bf16

    wp_cvt_kernel<<<REL * DIM / (256 * 4), 256, 0, stream>>>(Wp, WpB);
    proj_kernel<<<dim3(DIM/64, (DEP*BSZ)/64, 2), 256, 0, stream>>>(
        outs, graph, Wt, bt, P1, P2B);
    fused_kernel<<<DEP*BSZ, 128, 0, stream>>>(P1, P2B, WpB, bp, out);
}

// Round 5
// 160.972 us; speedup vs baseline: 2.2113x; 1.0185x over previous
//
#include <hip/hip_runtime.h>
#include <hip/hip_bf16.h>
#include <math.h>

#define DEP   96
#define HEADS 96
#define BSZ   16
#define DIM   512
#define REL   128
#define RELP  129   // REL + nil

typedef __attribute__((ext_vector_type(8))) short short8;
typedef __attribute__((ext_vector_type(4))) float floatx4;

__device__ __forceinline__ unsigned short f2bf(float x) {
    union { float f; unsigned int u; } c; c.f = x;
    unsigned int r = c.u + 0x7fffu + ((c.u >> 16) & 1u);   // RNE
    return (unsigned short)(r >> 16);
}
__device__ __forceinline__ float bflo2f(unsigned int u) {
    union { unsigned int u; float f; } c; c.u = u << 16; return c.f;
}
__device__ __forceinline__ float bfhi2f(unsigned int u) {
    union { unsigned int u; float f; } c; c.u = u & 0xffff0000u; return c.f;
}

// ---------------------------------------------------------------------------
// Kernel 0: fp32 -> bf16 for the WEIGHTS only (Wt: 24x staged per proj pass,
// Wp: 512x staged per fused pass). outs/graph stay f32 (A-side converts
// during proj staging; only 8x redundancy, keeps d_ws under the proven-safe
// 6.1 MB bound — R4's 8.6 MB overflowed ws_size and corrupted neighbor
// allocations, causing the post-timing divergence).
// 73728 chunks x 8 elems: [0,65536) -> Wt, [65536,73728) -> Wp.
// ---------------------------------------------------------------------------
__global__ __launch_bounds__(256) void cvt_kernel(
    const float* __restrict__ Wt, const float* __restrict__ Wp,
    unsigned short* __restrict__ WtB, unsigned short* __restrict__ WpB)
{
    const int chunk = blockIdx.x * 256 + threadIdx.x;
    const float* src; unsigned short* dst; int c;
    if (chunk < 65536) { src = Wt; dst = WtB; c = chunk; }
    else               { src = Wp; dst = WpB; c = chunk - 65536; }
    float4 a = *(const float4*)(src + (size_t)c * 8);
    float4 b = *(const float4*)(src + (size_t)c * 8 + 4);
    uint4 o;
    o.x = (unsigned)f2bf(a.x) | ((unsigned)f2bf(a.y) << 16);
    o.y = (unsigned)f2bf(a.z) | ((unsigned)f2bf(a.w) << 16);
    o.z = (unsigned)f2bf(b.x) | ((unsigned)f2bf(b.y) << 16);
    o.w = (unsigned)f2bf(b.z) | ((unsigned)f2bf(b.w) << 16);
    *(uint4*)(dst + (size_t)c * 8) = o;
}

#define PSS 72   // LDS row stride (bf16 elems): 144 B = 16B-aligned

// ---------------------------------------------------------------------------
// Kernel A: projections via bf16 MFMA. A cast-on-stage (f32 in), Wt pre-cast.
//   z=0: P1[m][n] = outs@Wt[:, :512]^T + bt   (f32 out)
//   z=1: P2B[m][n]= graph@Wt[:, 512:]^T       (bf16 out)
// 64x64 tile, BK=64, 256 threads = 4 waves; wave w owns m-rows [16w,16w+16).
// ---------------------------------------------------------------------------
__global__ __launch_bounds__(256) void proj_kernel(
    const float* __restrict__ outs, const float* __restrict__ graph,
    const unsigned short* __restrict__ WtB, const float* __restrict__ bt,
    float* __restrict__ P1, unsigned short* __restrict__ P2B)
{
    const int z = blockIdx.z;
    const float* A = z ? graph : outs;
    const int off  = z ? DIM : 0;
    const int row0 = blockIdx.y * 64;
    const int col0 = blockIdx.x * 64;

    __shared__ unsigned short As[64 * PSS];   // [m][k] bf16
    __shared__ unsigned short Ws[64 * PSS];   // [n][k] bf16

    const int tid  = threadIdx.x;
    const int lane = tid & 63;
    const int wv   = tid >> 6;          // 0..3
    const int ln15 = lane & 15;
    const int quad = lane >> 4;

    floatx4 acc[4];
    #pragma unroll
    for (int nt = 0; nt < 4; ++nt) acc[nt] = (floatx4){0.f,0.f,0.f,0.f};

    for (int kt = 0; kt < DIM; kt += 64) {
        // A: f32 load + RNE cast to bf16 LDS
        #pragma unroll
        for (int q = 0; q < 4; ++q) {
            const int slot = q*256 + tid;       // 0..1023
            const int r  = slot >> 4;           // 0..63
            const int e4 = (slot & 15) * 4;
            float4 v = *(const float4*)(A + (size_t)(row0 + r) * DIM + kt + e4);
            ushort4 o;
            o.x = f2bf(v.x); o.y = f2bf(v.y); o.z = f2bf(v.z); o.w = f2bf(v.w);
            *(ushort4*)&As[r * PSS + e4] = o;
        }
        // Wt: pure uint4 copy (pre-cast)
        #pragma unroll
        for (int q = 0; q < 2; ++q) {
            const int slot = q*256 + tid;       // 0..511
            const int r  = slot >> 3;           // 0..63
            const int e8 = (slot & 7) * 8;
            *(uint4*)&Ws[r * PSS + e8] =
                *(const uint4*)(WtB + (size_t)(col0 + r) * (2*DIM) + off + kt + e8);
        }
        __syncthreads();
        #pragma unroll
        for (int ks = 0; ks < 64; ks += 32) {
            short8 af = *(const short8*)&As[(wv*16 + ln15) * PSS + ks + quad*8];
            #pragma unroll
            for (int nt = 0; nt < 4; ++nt) {
                short8 bf8 = *(const short8*)&Ws[(nt*16 + ln15) * PSS + ks + quad*8];
                acc[nt] = __builtin_amdgcn_mfma_f32_16x16x32_bf16(af, bf8, acc[nt], 0, 0, 0);
            }
        }
        __syncthreads();
    }

    #pragma unroll
    for (int nt = 0; nt < 4; ++nt) {
        #pragma unroll
        for (int reg = 0; reg < 4; ++reg) {
            const int m = row0 + wv*16 + quad*4 + reg;
            const int n = col0 + nt*16 + ln15;
            float v = acc[nt][reg];
            if (!z) P1[(size_t)m * DIM + n] = v + bt[n];
            else    P2B[(size_t)m * DIM + n] = f2bf(v);
        }
    }
}

// ---------------------------------------------------------------------------
// Kernel B: fused pairwise relu + bf16-MFMA GEMM + log_softmax(129).
// One block per (d,b): C[96 m][128 n] = relu(drow + P2[h,b,:]) @ Wp^T.
// 256 threads = 4 waves; wave (mh=w&1, nh=w>>1) owns the 48m x 64n quadrant.
// Softmax: in-quad shuffle partials per 64-col half -> LDS -> combine w/ nil.
// ---------------------------------------------------------------------------
#define HSS 72
#define WSS 72

__global__ __launch_bounds__(256, 4) void fused_kernel(
    const float* __restrict__ P1, const unsigned short* __restrict__ P2B,
    const unsigned short* __restrict__ WpB, const float* __restrict__ bp,
    float* __restrict__ out)
{
    const int db = blockIdx.x;      // d*16 + b
    const int b  = db & 15;

    __shared__ float          drow[DIM];
    __shared__ unsigned short hs[96 * HSS];    // h tile  [m][k] bf16
    __shared__ unsigned short ws[128 * WSS];   // Wp tile [n][k] bf16
    __shared__ float          pmx[96][2];      // partial max per (row, col-half)
    __shared__ float          pl [96][2];      // partial sum-exp

    const int tid  = threadIdx.x;       // 0..255
    const int lane = tid & 63;
    const int wv   = tid >> 6;          // 0..3
    const int ln15 = lane & 15;
    const int quad = lane >> 4;
    const int mh   = wv & 1;            // row half: rows [48*mh, 48*mh+48)
    const int nh   = wv >> 1;           // col half: cols [64*nh, 64*nh+64)

    drow[tid]       = P1[(size_t)db * DIM + tid];
    drow[tid + 256] = P1[(size_t)db * DIM + tid + 256];
    __syncthreads();

    floatx4 acc[3][4];
    #pragma unroll
    for (int i = 0; i < 3; ++i)
        #pragma unroll
        for (int j = 0; j < 4; ++j) acc[i][j] = (floatx4){0.f,0.f,0.f,0.f};

    for (int kt = 0; kt < DIM; kt += 64) {
        // ---- stage hs[h][e] = bf16(relu(drow[e] + P2B[h,b,e])), 96x64 ----
        #pragma unroll
        for (int q = 0; q < 3; ++q) {
            const int slot = q*256 + tid;        // 0..767
            const int h  = slot >> 3;            // 0..95
            const int e8 = (slot & 7) * 8;
            uint4 pv = *(const uint4*)(P2B + ((size_t)h * BSZ + b) * DIM + kt + e8);
            float4 d0 = *(const float4*)&drow[kt + e8];
            float4 d1 = *(const float4*)&drow[kt + e8 + 4];
            float s0 = fmaxf(bflo2f(pv.x) + d0.x, 0.f);
            float s1 = fmaxf(bfhi2f(pv.x) + d0.y, 0.f);
            float s2 = fmaxf(bflo2f(pv.y) + d0.z, 0.f);
            float s3 = fmaxf(bfhi2f(pv.y) + d0.w, 0.f);
            float s4 = fmaxf(bflo2f(pv.z) + d1.x, 0.f);
            float s5 = fmaxf(bfhi2f(pv.z) + d1.y, 0.f);
            float s6 = fmaxf(bflo2f(pv.w) + d1.z, 0.f);
            float s7 = fmaxf(bfhi2f(pv.w) + d1.w, 0.f);
            uint4 o;
            o.x = (unsigned)f2bf(s0) | ((unsigned)f2bf(s1) << 16);
            o.y = (unsigned)f2bf(s2) | ((unsigned)f2bf(s3) << 16);
            o.z = (unsigned)f2bf(s4) | ((unsigned)f2bf(s5) << 16);
            o.w = (unsigned)f2bf(s6) | ((unsigned)f2bf(s7) << 16);
            *(uint4*)&hs[h * HSS + e8] = o;
        }
        // ---- stage ws[r][e] = WpB[r][kt+e], 128x64 (B-operand layout) ----
        #pragma unroll
        for (int q = 0; q < 4; ++q) {
            const int slot = q*256 + tid;        // 0..1023
            const int r = slot >> 3;
            const int g = (slot & 7) * 8;
            *(uint4*)&ws[r * WSS + g] =
                *(const uint4*)(WpB + (size_t)r * DIM + kt + g);
        }
        __syncthreads();

        #pragma unroll
        for (int ks = 0; ks < 64; ks += 32) {
            short8 af[3], bf8[4];
            #pragma unroll
            for (int mt = 0; mt < 3; ++mt)
                af[mt] = *(const short8*)&hs[(mh*48 + mt*16 + ln15) * HSS + ks + quad*8];
            #pragma unroll
            for (int nt = 0; nt < 4; ++nt)
                bf8[nt] = *(const short8*)&ws[(nh*64 + nt*16 + ln15) * WSS + ks + quad*8];
            #pragma unroll
            for (int nt = 0; nt < 4; ++nt)
                #pragma unroll
                for (int mt = 0; mt < 3; ++mt)
                    acc[mt][nt] = __builtin_amdgcn_mfma_f32_16x16x32_bf16(
                        af[mt], bf8[nt], acc[mt][nt], 0, 0, 0);
        }
        __syncthreads();
    }

    // ---- epilogue phase 1: per-quadrant softmax partials (no nil yet) ----
    float bpv[4];
    #pragma unroll
    for (int nt = 0; nt < 4; ++nt) bpv[nt] = bp[nh*64 + nt*16 + ln15];

    #pragma unroll
    for (int mt = 0; mt < 3; ++mt) {
        #pragma unroll
        for (int reg = 0; reg < 4; ++reg) {
            const int m = mh*48 + mt*16 + quad*4 + reg;
            float s[4];
            float mx = -1e30f;
            #pragma unroll
            for (int nt = 0; nt < 4; ++nt) {
                s[nt] = acc[mt][nt][reg] + bpv[nt];
                mx = fmaxf(mx, s[nt]);
            }
            #pragma unroll
            for (int msk = 1; msk < 16; msk <<= 1) mx = fmaxf(mx, __shfl_xor(mx, msk));
            float l = 0.f;
            #pragma unroll
            for (int nt = 0; nt < 4; ++nt) l += __expf(s[nt] - mx);
            #pragma unroll
            for (int msk = 1; msk < 16; msk <<= 1) l += __shfl_xor(l, msk);
            if (ln15 == 0) { pmx[m][nh] = mx; pl[m][nh] = l; }
        }
    }
    __syncthreads();

    // ---- epilogue phase 2: combine halves + nil, write out ----
    #pragma unroll
    for (int mt = 0; mt < 3; ++mt) {
        #pragma unroll
        for (int reg = 0; reg < 4; ++reg) {
            const int m = mh*48 + mt*16 + quad*4 + reg;
            const float mx0 = pmx[m][0], mx1 = pmx[m][1];
            const float l0  = pl[m][0],  l1  = pl[m][1];
            const float MX = fmaxf(fmaxf(mx0, mx1), 0.f);   // nil = 0 in max
            const float L  = l0 * __expf(mx0 - MX) + l1 * __expf(mx1 - MX)
                           + __expf(-MX);                    // nil term
            const float lse = MX + __logf(L);

            const size_t base = ((size_t)db * HEADS + m) * RELP;
            #pragma unroll
            for (int nt = 0; nt < 4; ++nt)
                out[base + 1 + nh*64 + nt*16 + ln15] = acc[mt][nt][reg] + bpv[nt] - lse;
            if (nh == 0 && ln15 == 0) out[base] = -lse;
        }
    }
}

extern "C" void kernel_launch(void* const* d_in, const int* in_sizes, int n_in,
                              void* d_out, int out_size, void* d_ws, size_t ws_size,
                              hipStream_t stream) {
    const float* outs  = (const float*)d_in[0];
    const float* graph = (const float*)d_in[1];
    const float* Wt    = (const float*)d_in[2];
    const float* bt    = (const float*)d_in[3];
    const float* Wp    = (const float*)d_in[4];
    const float* bp    = (const float*)d_in[5];
    float* out = (float*)d_out;

    // Workspace: 5,898,240 B total — under the proven-safe 6.1 MB (R2).
    float* P1           = (float*)d_ws;                     // [1536][512] f32   (3 MB)
    unsigned short* P2B = (unsigned short*)(P1 + 786432);   // [1536][512] bf16  (1.5 MB)
    unsigned short* WpB = P2B + 786432;                     // [128][512]  bf16  (128 KB)
    unsigned short* WtB = WpB + 65536;                      // [512][1024] bf16  (1 MB)

    cvt_kernel<<<288, 256, 0, stream>>>(Wt, Wp, WtB, WpB);
    proj_kernel<<<dim3(DIM/64, (DEP*BSZ)/64, 2), 256, 0, stream>>>(
        outs, graph, WtB, bt, P1, P2B);
    fused_kernel<<<DEP*BSZ, 256, 0, stream>>>(P1, P2B, WpB, bp, out);
}